// Round 22
// baseline (108.682 us; speedup 1.0000x reference)
//
#include <hip/hip_runtime.h>
#include <hip/hip_bf16.h>

#define HH 16
#define DD 128
#define NBQ 128
#define SS 8192

typedef __attribute__((ext_vector_type(4))) float f32x4;
typedef __attribute__((ext_vector_type(4))) short bf16x4;
typedef __attribute__((ext_vector_type(8))) short bf16x8;

// single-instruction HW convert (RNE)
__device__ __forceinline__ short f2bf_hw(float f) {
  __hip_bfloat16 b = __float2bfloat16(f);
  return __builtin_bit_cast(short, b);
}

__device__ __forceinline__ void gload_lds16(const void* g, void* l) {
  __builtin_amdgcn_global_load_lds(
      (const __attribute__((address_space(1))) void*)g,
      (__attribute__((address_space(3))) void*)l, 16, 0, 0);
}

// raw barrier with compile-time memory fences (no vmcnt drain)
__device__ __forceinline__ void wg_barrier() {
  asm volatile("" ::: "memory");
  __builtin_amdgcn_s_barrier();
  asm volatile("" ::: "memory");
}

// ---- prepass (round-15 proven): V fp32 -> bf16 PV-frag-ordered Vt2[h][kb][d][p] ----
// p = lg*16 + kt*4 + r  holds V[key = kt*16 + lg*4 + r][d]
__global__ __launch_bounds__(256)
void conv_vt2_kernel(const float* __restrict__ vg, unsigned short* __restrict__ vt) {
  __shared__ unsigned short tile[128 * 72];  // [d][key] with +8 short pad per row
  const int kb = blockIdx.x, h = blockIdx.y, tid = threadIdx.x;
  {
    const int r = tid >> 2, q = tid & 3;   // r = key row, q = d-chunk
    const float* vp = vg + ((size_t)(kb * 64 + r) * HH + h) * DD + q * 32;
    #pragma unroll
    for (int c = 0; c < 8; ++c) {
      f32x4 a = *(const f32x4*)(vp + c * 4);
      #pragma unroll
      for (int j = 0; j < 4; ++j)
        tile[(q * 32 + c * 4 + j) * 72 + r] = (unsigned short)f2bf_hw(a[j]);
    }
  }
  __syncthreads();
  const int d = tid >> 1, half = tid & 1;
  unsigned short* op = vt + ((size_t)(h * NBQ + kb) * 128 + d) * 64 + half * 32;
  #pragma unroll
  for (int j = 0; j < 4; ++j) {
    bf16x8 f;
    #pragma unroll
    for (int e = 0; e < 8; ++e) {
      const int p = half * 32 + j * 8 + e;
      const int key = ((p >> 2) & 3) * 16 + (p >> 4) * 4 + (p & 3);
      f[e] = (short)tile[d * 72 + key];
    }
    *(bf16x8*)(op + j * 8) = f;
  }
}

// ---------- main kernel: v20 skeleton + pipelined inline-K (no K prepass) ----------
// Per iter t: [vmcnt(4 if K(t+1) regs in flight else 0) + lgkmcnt(0)] -> barrier ->
// issue V(t+1) gload -> QK(t) -> cvt+write K(t+1) (regs loaded ~1.5 iters ago) ->
// issue K(t+2) fp32 loads into the SAME regs -> softmax/PV. Counted waits: the
// pre-barrier vmcnt passes only the (older) V gloads; K loads stay in flight and are
// waited implicitly at cvt with ~1.5 iterations of slack (covers HBM latency).
#define SWK(o) ((o) ^ ((((o) >> 8) & 7) << 4))
#define SWV(o) ((o) ^ ((((o) >> 7) & 7) << 4))

__global__ __launch_bounds__(512, 2)
void sparse_attn_v21(const float* __restrict__ qg_, const float* __restrict__ kg,
                     const unsigned short* __restrict__ vtbuf, float* __restrict__ outg) {
  extern __shared__ __align__(16) char lds[];
  // K buf b: b*16384 ([64 key][128 d] bf16 swz) | V buf b: 32768 + b*16384 (Vt2 swz)

  const int bx   = blockIdx.x;
  const int w    = (bx & 7) * 128 + (bx >> 3);  // XCD-contiguous work index
  const int h    = w >> 6;
  const int qgrp = w & 63;
  const int tid  = threadIdx.x;
  const int wid  = tid >> 6;     // 0..7
  const int lane = tid & 63;
  const int l15  = lane & 15;
  const int lg   = lane >> 4;

  const int qlo  = qgrp * 2, qhi = qgrp * 2 + 1;
  const int qb_w = qlo + (wid >> 2);          // this wave's q-block (4 waves per block)
  const int rib0 = (wid & 3) * 16;            // wave's row base within its q-block

  const int nv     = (qhi + 1 < 4) ? qhi + 1 : 4;
  const int wstart = (qlo - 3 > 4) ? qlo - 3 : 4;
  const int nw     = (qhi - wstart + 1 > 0) ? qhi - wstart + 1 : 0;
  const int nlist  = nv + nw;                 // >= 2 always

  // 1/sqrt(128) * log2(e): exp2-domain softmax
  const float scale = 0.12752030522080552f;

  const int rowg = qgrp * 128 + (wid >> 2) * 64 + rib0;   // global row base of this wave

  // ---- Q fragments (B operand: col j = q-row = l15, k = d = kc*32+lg*8+{0..7}) ----
  bf16x8 qa[4];
  {
    const float* qp = qg_ + ((size_t)(rowg + l15) * HH + h) * DD;
    #pragma unroll
    for (int kc = 0; kc < 4; ++kc) {
      const int d0 = kc * 32 + lg * 8;
      f32x4 a = *(const f32x4*)(qp + d0);
      f32x4 b = *(const f32x4*)(qp + d0 + 4);
      bf16x8 f;
      f[0] = f2bf_hw(a[0] * scale); f[1] = f2bf_hw(a[1] * scale);
      f[2] = f2bf_hw(a[2] * scale); f[3] = f2bf_hw(a[3] * scale);
      f[4] = f2bf_hw(b[0] * scale); f[5] = f2bf_hw(b[1] * scale);
      f[6] = f2bf_hw(b[2] * scale); f[7] = f2bf_hw(b[3] * scale);
      qa[kc] = f;
    }
  }

  // oa[nd][r] = O[q-row = lg*4+r (within 16-row tile)][d = nd*16+l15]
  f32x4 oa[8];
  #pragma unroll
  for (int i = 0; i < 8; ++i) oa[i] = (f32x4){0.f, 0.f, 0.f, 0.f};
  float mr = -1e30f;   // running row max, keyed q-row = l15 (row-uniform)
  float lr = 0.f;      // lane-partial row sum, keyed l15

  const char* vbase = (const char*)vtbuf + ((size_t)h * NBQ << 14);
  const int o0 = wid * 1024 + lane * 16;   // V gload slot within an 8KB round

  // ---- inline-K staging geometry: thread owns K[key = tid>>3][d = (tid&7)*16 .. +15]
  //      = LDS bf16 bytes [tid*32, +32), each 16B half swizzled separately ----
  const int kkey = tid >> 3;
  const int kd0  = (tid & 7) * 16;
  const int kob0 = SWK(tid * 32);
  const int kob1 = SWK(tid * 32 + 16);
  // fp32 K source for block kb: kg + ((kb*64 + kkey)*HH + h)*DD + kd0
  const float* ksrc0 = kg + (((size_t)kkey) * HH + h) * DD + kd0;  // block 0 base
  const size_t kblkstride = (size_t)64 * HH * DD;                  // fp32 elems per block

  f32x4 ks0, ks1, ks2, ks3;   // staged K fp32 (one set, reloaded each iteration)

  // ---- prologue ----
  {
    // K(0): load (waits only its own 4 loads), cvt, write Kbuf0
    const float* kp = ksrc0;  // list[0] = block 0
    f32x4 a0 = *(const f32x4*)(kp);
    f32x4 a1 = *(const f32x4*)(kp + 4);
    f32x4 a2 = *(const f32x4*)(kp + 8);
    f32x4 a3 = *(const f32x4*)(kp + 12);
    // V(0) gloads issued AFTER the K(0) loads so the cvt's implicit wait can leave them in flight
    #pragma unroll
    for (int p = 0; p < 2; ++p) {
      const int o = p * 8192 + o0;
      gload_lds16(vbase + SWV(o), lds + 32768 + p * 8192 + wid * 1024);
    }
    bf16x8 w0, w1;
    w0[0] = f2bf_hw(a0[0]); w0[1] = f2bf_hw(a0[1]); w0[2] = f2bf_hw(a0[2]); w0[3] = f2bf_hw(a0[3]);
    w0[4] = f2bf_hw(a1[0]); w0[5] = f2bf_hw(a1[1]); w0[6] = f2bf_hw(a1[2]); w0[7] = f2bf_hw(a1[3]);
    w1[0] = f2bf_hw(a2[0]); w1[1] = f2bf_hw(a2[1]); w1[2] = f2bf_hw(a2[2]); w1[3] = f2bf_hw(a2[3]);
    w1[4] = f2bf_hw(a3[0]); w1[5] = f2bf_hw(a3[1]); w1[6] = f2bf_hw(a3[2]); w1[7] = f2bf_hw(a3[3]);
    *(bf16x8*)(lds + kob0) = w0;
    *(bf16x8*)(lds + kob1) = w1;
    // issue K(list[1]) loads into ks regs (nlist >= 2 always); no wait
    const int kb1 = (1 < nv) ? 1 : wstart;
    const float* kp1 = ksrc0 + (size_t)kb1 * kblkstride;
    ks0 = *(const f32x4*)(kp1);
    ks1 = *(const f32x4*)(kp1 + 4);
    ks2 = *(const f32x4*)(kp1 + 8);
    ks3 = *(const f32x4*)(kp1 + 12);
  }

  for (int t = 0; t < nlist; ++t) {
    const int kb = (t < nv) ? t : (wstart + (t - nv));
    const bool valid = (kb <= qb_w) && ((qb_w - kb < 4) || (kb < 4));
    char* Kb = lds + (t & 1) * 16384;
    char* Vb = lds + 32768 + (t & 1) * 16384;
    const bool havenext = (t + 1 < nlist);

    // ---- wait: V(t) gloads done (oldest in FIFO); K(t+1) fp32 loads may stay in
    // ---- flight (vmcnt(4)); lgkm(0) so every wave's K ds_writes are visible ----
    if (havenext) {
      asm volatile("s_waitcnt vmcnt(4) lgkmcnt(0)" ::: "memory");
    } else {
      asm volatile("s_waitcnt vmcnt(0) lgkmcnt(0)" ::: "memory");
    }
    wg_barrier();   // stage(t) visible everywhere AND compute(t-1) done

    // ---- issue V(t+1) gloads (buffer's last readers finished before the barrier) ----
    if (havenext) {
      const int kbn = (t + 1 < nv) ? (t + 1) : (wstart + (t + 1 - nv));
      const char* vsrc = vbase + ((size_t)kbn << 14);
      char* Vd = lds + 32768 + ((t + 1) & 1) * 16384;
      #pragma unroll
      for (int p = 0; p < 2; ++p) {
        const int o = p * 8192 + o0;
        gload_lds16(vsrc + SWV(o), Vd + p * 8192 + wid * 1024);
      }
    }

    // ---- S^T = K Q^T : s[kt][r] = S[q=l15][key = kt*16+lg*4+r] ----
    f32x4 s[4];
    if (valid) {
      #pragma unroll
      for (int kt = 0; kt < 4; ++kt) s[kt] = (f32x4){0.f, 0.f, 0.f, 0.f};
      __builtin_amdgcn_s_setprio(1);
      #pragma unroll
      for (int kt = 0; kt < 4; ++kt) {
        const int key = kt * 16 + l15;   // A-frag row = l15
        #pragma unroll
        for (int kc = 0; kc < 4; ++kc) {
          const int off = (key * 256 + (kc * 32 + lg * 8) * 2) ^ ((key & 7) << 4);
          bf16x8 kf = *(const bf16x8*)(Kb + off);   // A: K[key][d]
          s[kt] = __builtin_amdgcn_mfma_f32_16x16x32_bf16(kf, qa[kc], s[kt], 0, 0, 0);
        }
      }
      __builtin_amdgcn_s_setprio(0);
    }

    // ---- cvt + write K(t+1) from regs (loaded ~1.5 iters ago; implicit wait leaves
    // ---- the newer V(t+1) gloads in flight), then reload regs with K(t+2) ----
    if (havenext) {
      char* Kd = lds + ((t + 1) & 1) * 16384;
      bf16x8 w0, w1;
      w0[0] = f2bf_hw(ks0[0]); w0[1] = f2bf_hw(ks0[1]); w0[2] = f2bf_hw(ks0[2]); w0[3] = f2bf_hw(ks0[3]);
      w0[4] = f2bf_hw(ks1[0]); w0[5] = f2bf_hw(ks1[1]); w0[6] = f2bf_hw(ks1[2]); w0[7] = f2bf_hw(ks1[3]);
      w1[0] = f2bf_hw(ks2[0]); w1[1] = f2bf_hw(ks2[1]); w1[2] = f2bf_hw(ks2[2]); w1[3] = f2bf_hw(ks2[3]);
      w1[4] = f2bf_hw(ks3[0]); w1[5] = f2bf_hw(ks3[1]); w1[6] = f2bf_hw(ks3[2]); w1[7] = f2bf_hw(ks3[3]);
      *(bf16x8*)(Kd + kob0) = w0;
      *(bf16x8*)(Kd + kob1) = w1;
      if (t + 2 < nlist) {
        const int kb2 = (t + 2 < nv) ? (t + 2) : (wstart + (t + 2 - nv));
        const float* kp2 = ksrc0 + (size_t)kb2 * kblkstride;
        ks0 = *(const f32x4*)(kp2);
        ks1 = *(const f32x4*)(kp2 + 4);
        ks2 = *(const f32x4*)(kp2 + 8);
        ks3 = *(const f32x4*)(kp2 + 12);
      }
    }

    if (valid) {
      // ---- diagonal block: element-level causal mask (q = l15, key = kt*16+lg*4+r) ----
      if (kb == qb_w) {
        const int rib = rib0 + l15;   // q-row within block
        #pragma unroll
        for (int kt = 0; kt < 4; ++kt)
          #pragma unroll
          for (int r = 0; r < 4; ++r) {
            const int key = kt * 16 + lg * 4 + r;
            if (rib < key) s[kt][r] = -1e30f;
          }
      }

      // ---- softmax (exp2 domain, defer-max THR=8, lane-partial sum) ----
      {
        float a0 = fmaxf(fmaxf(s[0][0], s[0][1]), fmaxf(s[0][2], s[0][3]));
        float a1 = fmaxf(fmaxf(s[1][0], s[1][1]), fmaxf(s[1][2], s[1][3]));
        float a2 = fmaxf(fmaxf(s[2][0], s[2][1]), fmaxf(s[2][2], s[2][3]));
        float a3 = fmaxf(fmaxf(s[3][0], s[3][1]), fmaxf(s[3][2], s[3][3]));
        float lanemax = fmaxf(fmaxf(a0, a1), fmaxf(a2, a3));
        if (!__all(lanemax <= mr + 8.f)) {
          float mx = lanemax;
          mx = fmaxf(mx, __shfl_xor(mx, 16));
          mx = fmaxf(mx, __shfl_xor(mx, 32));     // row max (uniform across lg)
          const float mnew = fmaxf(mr, mx);
          const float sc = __builtin_amdgcn_exp2f(mr - mnew);
          lr *= sc;
          mr = mnew;
          // transpose sc to oa rows: row (lg*4+r)'s sc lives in lane (lg*4+r)
          const float s0 = __shfl(sc, lg * 4 + 0);
          const float s1 = __shfl(sc, lg * 4 + 1);
          const float s2 = __shfl(sc, lg * 4 + 2);
          const float s3 = __shfl(sc, lg * 4 + 3);
          #pragma unroll
          for (int nd = 0; nd < 8; ++nd) {
            oa[nd][0] *= s0; oa[nd][1] *= s1;
            oa[nd][2] *= s2; oa[nd][3] *= s3;
          }
        }
        float lsum = 0.f;
        #pragma unroll
        for (int kt = 0; kt < 4; ++kt)
          #pragma unroll
          for (int r = 0; r < 4; ++r) {
            const float p = __builtin_amdgcn_exp2f(s[kt][r] - mr);
            s[kt][r] = p;
            lsum += p;
          }
        lr += lsum;
      }

      // ---- pack P in-register: pa[kt] = A-frag (row=l15, k=lg*4+{0..3}) ----
      bf16x4 pa[4];
      #pragma unroll
      for (int kt = 0; kt < 4; ++kt) {
        unsigned u0 = (unsigned)(unsigned short)f2bf_hw(s[kt][0]) |
                      ((unsigned)(unsigned short)f2bf_hw(s[kt][1]) << 16);
        unsigned u1 = (unsigned)(unsigned short)f2bf_hw(s[kt][2]) |
                      ((unsigned)(unsigned short)f2bf_hw(s[kt][3]) << 16);
        uint2 uu; uu.x = u0; uu.y = u1;
        pa[kt] = __builtin_bit_cast(bf16x4, uu);
      }

      // ---- O += P V : b128 reads (Vt2 layout), 2 K-step frags per read ----
      __builtin_amdgcn_s_setprio(1);
      #pragma unroll
      for (int nd = 0; nd < 8; ++nd) {
        const int d = nd * 16 + l15;
        #pragma unroll
        for (int hb = 0; hb < 2; ++hb) {
          const int off = (d * 128 + lg * 32 + hb * 16) ^ ((d & 7) << 4);
          bf16x8 v2 = *(const bf16x8*)(Vb + off);
          bf16x4 vlo = __builtin_shufflevector(v2, v2, 0, 1, 2, 3);
          bf16x4 vhi = __builtin_shufflevector(v2, v2, 4, 5, 6, 7);
          oa[nd] = __builtin_amdgcn_mfma_f32_16x16x16bf16_1k(pa[2 * hb],     vlo, oa[nd], 0, 0, 0);
          oa[nd] = __builtin_amdgcn_mfma_f32_16x16x16bf16_1k(pa[2 * hb + 1], vhi, oa[nd], 0, 0, 0);
        }
      }
      __builtin_amdgcn_s_setprio(0);
    }
    // no trailing barrier: next iteration's single barrier provides the ordering
  }

  // ---- epilogue: reduce lr (keyed l15) across lg, transpose inv to oa rows, store ----
  {
    float l = lr;
    l += __shfl_xor(l, 16);
    l += __shfl_xor(l, 32);
    const float inv = 1.0f / l;                 // keyed l15
    const float i0 = __shfl(inv, lg * 4 + 0);   // row lg*4+r's inv from lane lg*4+r
    const float i1 = __shfl(inv, lg * 4 + 1);
    const float i2 = __shfl(inv, lg * 4 + 2);
    const float i3 = __shfl(inv, lg * 4 + 3);
    float* op = outg + ((size_t)rowg * HH + h) * DD;
    #pragma unroll
    for (int nd = 0; nd < 8; ++nd) {
      const int d = nd * 16 + l15;
      op[(size_t)(lg * 4 + 0) * HH * DD + d] = oa[nd][0] * i0;
      op[(size_t)(lg * 4 + 1) * HH * DD + d] = oa[nd][1] * i1;
      op[(size_t)(lg * 4 + 2) * HH * DD + d] = oa[nd][2] * i2;
      op[(size_t)(lg * 4 + 3) * HH * DD + d] = oa[nd][3] * i3;
    }
  }
}

extern "C" void kernel_launch(void* const* d_in, const int* in_sizes, int n_in,
                              void* d_out, int out_size, void* d_ws, size_t ws_size,
                              hipStream_t stream) {
  const float* q = (const float*)d_in[0];
  const float* k = (const float*)d_in[1];
  const float* v = (const float*)d_in[2];
  float* out = (float*)d_out;
  unsigned short* vtbuf = (unsigned short*)d_ws;

  conv_vt2_kernel<<<dim3(NBQ, HH), 256, 0, stream>>>(v, vtbuf);
  sparse_attn_v21<<<dim3(NBQ / 2 * HH), 512, 65536, stream>>>(q, k, vtbuf, out);
}

// Round 23
// 101.980 us; speedup vs baseline: 1.0657x; 1.0657x over previous
//
#include <hip/hip_runtime.h>
#include <hip/hip_bf16.h>

#define HH 16
#define DD 128
#define NBQ 128
#define SS 8192

typedef __attribute__((ext_vector_type(4))) float f32x4;
typedef __attribute__((ext_vector_type(4))) short bf16x4;
typedef __attribute__((ext_vector_type(8))) short bf16x8;

// single-instruction HW convert (RNE)
__device__ __forceinline__ short f2bf_hw(float f) {
  __hip_bfloat16 b = __float2bfloat16(f);
  return __builtin_bit_cast(short, b);
}

__device__ __forceinline__ void gload_lds16(const void* g, void* l) {
  __builtin_amdgcn_global_load_lds(
      (const __attribute__((address_space(1))) void*)g,
      (__attribute__((address_space(3))) void*)l, 16, 0, 0);
}

// raw barrier with compile-time memory fences (no vmcnt drain)
__device__ __forceinline__ void wg_barrier() {
  asm volatile("" ::: "memory");
  __builtin_amdgcn_s_barrier();
  asm volatile("" ::: "memory");
}

// ---- GRID-fused prepass: blocks [0,2048) = V->Vt2 transpose; [2048, 2048+16384) = K convert ----
// Each path is the round-15-proven code verbatim; V blocks first (heavier).
// Static 18KB LDS: V path uses it; K path ignores it (8 wg/CU either way -> no occupancy loss).
__global__ __launch_bounds__(256)
void conv_fused_kernel(const float* __restrict__ kg, const float* __restrict__ vg,
                       unsigned short* __restrict__ kbuf, unsigned short* __restrict__ vt) {
  __shared__ unsigned short tile[128 * 72];  // [d][key] with +8 short pad per row
  const int bx  = blockIdx.x;
  const int tid = threadIdx.x;
  if (bx < 2048) {
    // ---- V path: fp32 [s][h][d] -> bf16 Vt2[h][kb][d][p], p = lg*16+kt*4+r ----
    const int kb = bx & 127, h = bx >> 7;
    {
      const int r = tid >> 2, q = tid & 3;   // r = key row, q = d-chunk
      const float* vp = vg + ((size_t)(kb * 64 + r) * HH + h) * DD + q * 32;
      #pragma unroll
      for (int c = 0; c < 8; ++c) {
        f32x4 a = *(const f32x4*)(vp + c * 4);
        #pragma unroll
        for (int j = 0; j < 4; ++j)
          tile[(q * 32 + c * 4 + j) * 72 + r] = (unsigned short)f2bf_hw(a[j]);
      }
    }
    __syncthreads();
    const int d = tid >> 1, half = tid & 1;
    unsigned short* op = vt + ((size_t)(h * NBQ + kb) * 128 + d) * 64 + half * 32;
    #pragma unroll
    for (int j = 0; j < 4; ++j) {
      bf16x8 f;
      #pragma unroll
      for (int e = 0; e < 8; ++e) {
        const int p = half * 32 + j * 8 + e;
        const int key = ((p >> 2) & 3) * 16 + (p >> 4) * 4 + (p & 3);
        f[e] = (short)tile[d * 72 + key];
      }
      *(bf16x8*)(op + j * 8) = f;
    }
  } else {
    // ---- K path: fp32 [s][h][d] -> bf16 [h][s][d] ----
    const size_t e = ((size_t)(bx - 2048) * 256 + tid) * 4;  // out element idx
    const int h = (int)(e >> 20);           // S*D = 2^20
    const int s = (int)((e >> 7) & (SS - 1));
    const int d = (int)(e & 127);
    f32x4 a = *(const f32x4*)(kg + ((size_t)s * HH + h) * DD + d);
    bf16x4 o;
    o[0] = f2bf_hw(a[0]); o[1] = f2bf_hw(a[1]);
    o[2] = f2bf_hw(a[2]); o[3] = f2bf_hw(a[3]);
    *(bf16x4*)(kbuf + e) = o;
  }
}

// ---------- main kernel: v20 verbatim (measured best main: ~75 us) ----------
// Single barrier per iter: vmcnt(0) [waits stage(t), issued post-barrier in iter t-1 ->
// had all of compute(t-1) to land, ~free] -> barrier [stage(t) visible AND compute(t-1)
// done] -> issue stage(t+1) -> compute(t). 64KB LDS (K dbuf @0, V dbuf @32768) -> 2 wg/CU.
// 8 waves x 16 rows; XCD-contiguous swizzle; swapped QK^T; in-register P; Vt2 PV.
#define SWK(o) ((o) ^ ((((o) >> 8) & 7) << 4))
#define SWV(o) ((o) ^ ((((o) >> 7) & 7) << 4))

__global__ __launch_bounds__(512, 4)
void sparse_attn_v22(const float* __restrict__ qg_, const unsigned short* __restrict__ kbuf,
                     const unsigned short* __restrict__ vtbuf, float* __restrict__ outg) {
  extern __shared__ __align__(16) char lds[];
  // K buf b: b*16384 ([64 key][128 d] bf16 swz) | V buf b: 32768 + b*16384 (Vt2 swz)

  const int bx   = blockIdx.x;
  const int w    = (bx & 7) * 128 + (bx >> 3);  // XCD-contiguous work index
  const int h    = w >> 6;
  const int qgrp = w & 63;
  const int tid  = threadIdx.x;
  const int wid  = tid >> 6;     // 0..7
  const int lane = tid & 63;
  const int l15  = lane & 15;
  const int lg   = lane >> 4;

  const int qlo  = qgrp * 2, qhi = qgrp * 2 + 1;
  const int qb_w = qlo + (wid >> 2);          // this wave's q-block (4 waves per block)
  const int rib0 = (wid & 3) * 16;            // wave's row base within its q-block

  const int nv     = (qhi + 1 < 4) ? qhi + 1 : 4;
  const int wstart = (qlo - 3 > 4) ? qlo - 3 : 4;
  const int nw     = (qhi - wstart + 1 > 0) ? qhi - wstart + 1 : 0;
  const int nlist  = nv + nw;                 // >= 2 always

  // 1/sqrt(128) * log2(e): exp2-domain softmax
  const float scale = 0.12752030522080552f;

  const int rowg = qgrp * 128 + (wid >> 2) * 64 + rib0;   // global row base of this wave

  // ---- Q fragments (B operand: col j = q-row = l15, k = d = kc*32+lg*8+{0..7}) ----
  bf16x8 qa[4];
  {
    const float* qp = qg_ + ((size_t)(rowg + l15) * HH + h) * DD;
    #pragma unroll
    for (int kc = 0; kc < 4; ++kc) {
      const int d0 = kc * 32 + lg * 8;
      f32x4 a = *(const f32x4*)(qp + d0);
      f32x4 b = *(const f32x4*)(qp + d0 + 4);
      bf16x8 f;
      f[0] = f2bf_hw(a[0] * scale); f[1] = f2bf_hw(a[1] * scale);
      f[2] = f2bf_hw(a[2] * scale); f[3] = f2bf_hw(a[3] * scale);
      f[4] = f2bf_hw(b[0] * scale); f[5] = f2bf_hw(b[1] * scale);
      f[6] = f2bf_hw(b[2] * scale); f[7] = f2bf_hw(b[3] * scale);
      qa[kc] = f;
    }
  }

  // oa[nd][r] = O[q-row = lg*4+r (within 16-row tile)][d = nd*16+l15]
  f32x4 oa[8];
  #pragma unroll
  for (int i = 0; i < 8; ++i) oa[i] = (f32x4){0.f, 0.f, 0.f, 0.f};
  float mr = -1e30f;   // running row max, keyed q-row = l15 (row-uniform)
  float lr = 0.f;      // lane-partial row sum, keyed l15

  const char* kbase = (const char*)kbuf + ((size_t)h * NBQ << 14);
  const char* vbase = (const char*)vtbuf + ((size_t)h * NBQ << 14);
  const int o0 = wid * 1024 + lane * 16;   // thread's 16B slot within an 8KB round

  // prologue: issue stage(0) into buf 0 (no wait here; iter 0's vmcnt covers it)
  {
    #pragma unroll
    for (int p = 0; p < 2; ++p) {
      const int o = p * 8192 + o0;
      gload_lds16(kbase + SWK(o), lds + p * 8192 + wid * 1024);
    }
    #pragma unroll
    for (int p = 0; p < 2; ++p) {
      const int o = p * 8192 + o0;
      gload_lds16(vbase + SWV(o), lds + 32768 + p * 8192 + wid * 1024);
    }
  }

  for (int t = 0; t < nlist; ++t) {
    const int kb = (t < nv) ? t : (wstart + (t - nv));
    const bool valid = (kb <= qb_w) && ((qb_w - kb < 4) || (kb < 4));
    char* Kb = lds + (t & 1) * 16384;
    char* Vb = lds + 32768 + (t & 1) * 16384;
    const bool havenext = (t + 1 < nlist);

    // ---- wait own stage(t) (issued a full iteration ago -> ~free), then the single
    // ---- barrier: stage(t) visible everywhere AND compute(t-1) done ----
    asm volatile("s_waitcnt vmcnt(0)" ::: "memory");
    wg_barrier();

    // ---- issue stage(t+1) into the other buffers (their last readers, compute(t-1),
    // ---- finished before the barrier above) ----
    if (havenext) {
      const int kbn = (t + 1 < nv) ? (t + 1) : (wstart + (t + 1 - nv));
      const char* ksrc = kbase + ((size_t)kbn << 14);
      const char* vsrc = vbase + ((size_t)kbn << 14);
      char* Kd = lds + ((t + 1) & 1) * 16384;
      char* Vd = lds + 32768 + ((t + 1) & 1) * 16384;
      #pragma unroll
      for (int p = 0; p < 2; ++p) {
        const int o = p * 8192 + o0;
        gload_lds16(ksrc + SWK(o), Kd + p * 8192 + wid * 1024);
      }
      #pragma unroll
      for (int p = 0; p < 2; ++p) {
        const int o = p * 8192 + o0;
        gload_lds16(vsrc + SWV(o), Vd + p * 8192 + wid * 1024);
      }
    }

    if (valid) {
      // ---- S^T = K Q^T : s[kt][r] = S[q=l15][key = kt*16+lg*4+r] ----
      f32x4 s[4];
      #pragma unroll
      for (int kt = 0; kt < 4; ++kt) s[kt] = (f32x4){0.f, 0.f, 0.f, 0.f};
      __builtin_amdgcn_s_setprio(1);
      #pragma unroll
      for (int kt = 0; kt < 4; ++kt) {
        const int key = kt * 16 + l15;   // A-frag row = l15
        #pragma unroll
        for (int kc = 0; kc < 4; ++kc) {
          const int off = (key * 256 + (kc * 32 + lg * 8) * 2) ^ ((key & 7) << 4);
          bf16x8 kf = *(const bf16x8*)(Kb + off);   // A: K[key][d]
          s[kt] = __builtin_amdgcn_mfma_f32_16x16x32_bf16(kf, qa[kc], s[kt], 0, 0, 0);
        }
      }
      __builtin_amdgcn_s_setprio(0);

      // ---- diagonal block: element-level causal mask (q = l15, key = kt*16+lg*4+r) ----
      if (kb == qb_w) {
        const int rib = rib0 + l15;   // q-row within block
        #pragma unroll
        for (int kt = 0; kt < 4; ++kt)
          #pragma unroll
          for (int r = 0; r < 4; ++r) {
            const int key = kt * 16 + lg * 4 + r;
            if (rib < key) s[kt][r] = -1e30f;
          }
      }

      // ---- softmax (exp2 domain, defer-max THR=8, lane-partial sum) ----
      {
        float a0 = fmaxf(fmaxf(s[0][0], s[0][1]), fmaxf(s[0][2], s[0][3]));
        float a1 = fmaxf(fmaxf(s[1][0], s[1][1]), fmaxf(s[1][2], s[1][3]));
        float a2 = fmaxf(fmaxf(s[2][0], s[2][1]), fmaxf(s[2][2], s[2][3]));
        float a3 = fmaxf(fmaxf(s[3][0], s[3][1]), fmaxf(s[3][2], s[3][3]));
        float lanemax = fmaxf(fmaxf(a0, a1), fmaxf(a2, a3));
        if (!__all(lanemax <= mr + 8.f)) {
          float mx = lanemax;
          mx = fmaxf(mx, __shfl_xor(mx, 16));
          mx = fmaxf(mx, __shfl_xor(mx, 32));     // row max (uniform across lg)
          const float mnew = fmaxf(mr, mx);
          const float sc = __builtin_amdgcn_exp2f(mr - mnew);
          lr *= sc;
          mr = mnew;
          // transpose sc to oa rows: row (lg*4+r)'s sc lives in lane (lg*4+r)
          const float s0 = __shfl(sc, lg * 4 + 0);
          const float s1 = __shfl(sc, lg * 4 + 1);
          const float s2 = __shfl(sc, lg * 4 + 2);
          const float s3 = __shfl(sc, lg * 4 + 3);
          #pragma unroll
          for (int nd = 0; nd < 8; ++nd) {
            oa[nd][0] *= s0; oa[nd][1] *= s1;
            oa[nd][2] *= s2; oa[nd][3] *= s3;
          }
        }
        float lsum = 0.f;
        #pragma unroll
        for (int kt = 0; kt < 4; ++kt)
          #pragma unroll
          for (int r = 0; r < 4; ++r) {
            const float p = __builtin_amdgcn_exp2f(s[kt][r] - mr);
            s[kt][r] = p;
            lsum += p;
          }
        lr += lsum;
      }

      // ---- pack P in-register: pa[kt] = A-frag (row=l15, k=lg*4+{0..3}) ----
      bf16x4 pa[4];
      #pragma unroll
      for (int kt = 0; kt < 4; ++kt) {
        unsigned u0 = (unsigned)(unsigned short)f2bf_hw(s[kt][0]) |
                      ((unsigned)(unsigned short)f2bf_hw(s[kt][1]) << 16);
        unsigned u1 = (unsigned)(unsigned short)f2bf_hw(s[kt][2]) |
                      ((unsigned)(unsigned short)f2bf_hw(s[kt][3]) << 16);
        uint2 uu; uu.x = u0; uu.y = u1;
        pa[kt] = __builtin_bit_cast(bf16x4, uu);
      }

      // ---- O += P V : b128 reads (Vt2 layout), 2 K-step frags per read ----
      __builtin_amdgcn_s_setprio(1);
      #pragma unroll
      for (int nd = 0; nd < 8; ++nd) {
        const int d = nd * 16 + l15;
        #pragma unroll
        for (int hb = 0; hb < 2; ++hb) {
          const int off = (d * 128 + lg * 32 + hb * 16) ^ ((d & 7) << 4);
          bf16x8 v2 = *(const bf16x8*)(Vb + off);
          bf16x4 vlo = __builtin_shufflevector(v2, v2, 0, 1, 2, 3);
          bf16x4 vhi = __builtin_shufflevector(v2, v2, 4, 5, 6, 7);
          oa[nd] = __builtin_amdgcn_mfma_f32_16x16x16bf16_1k(pa[2 * hb],     vlo, oa[nd], 0, 0, 0);
          oa[nd] = __builtin_amdgcn_mfma_f32_16x16x16bf16_1k(pa[2 * hb + 1], vhi, oa[nd], 0, 0, 0);
        }
      }
      __builtin_amdgcn_s_setprio(0);
    }
    // no trailing barrier: next iteration's single barrier provides the ordering
  }

  // ---- epilogue: reduce lr (keyed l15) across lg, transpose inv to oa rows, store ----
  {
    float l = lr;
    l += __shfl_xor(l, 16);
    l += __shfl_xor(l, 32);
    const float inv = 1.0f / l;                 // keyed l15
    const float i0 = __shfl(inv, lg * 4 + 0);   // row lg*4+r's inv from lane lg*4+r
    const float i1 = __shfl(inv, lg * 4 + 1);
    const float i2 = __shfl(inv, lg * 4 + 2);
    const float i3 = __shfl(inv, lg * 4 + 3);
    float* op = outg + ((size_t)rowg * HH + h) * DD;
    #pragma unroll
    for (int nd = 0; nd < 8; ++nd) {
      const int d = nd * 16 + l15;
      op[(size_t)(lg * 4 + 0) * HH * DD + d] = oa[nd][0] * i0;
      op[(size_t)(lg * 4 + 1) * HH * DD + d] = oa[nd][1] * i1;
      op[(size_t)(lg * 4 + 2) * HH * DD + d] = oa[nd][2] * i2;
      op[(size_t)(lg * 4 + 3) * HH * DD + d] = oa[nd][3] * i3;
    }
  }
}

extern "C" void kernel_launch(void* const* d_in, const int* in_sizes, int n_in,
                              void* d_out, int out_size, void* d_ws, size_t ws_size,
                              hipStream_t stream) {
  const float* q = (const float*)d_in[0];
  const float* k = (const float*)d_in[1];
  const float* v = (const float*)d_in[2];
  float* out = (float*)d_out;
  const size_t elems = (size_t)HH * SS * DD;
  unsigned short* kbuf  = (unsigned short*)d_ws;
  unsigned short* vtbuf = kbuf + elems;

  conv_fused_kernel<<<2048 + (int)(elems / 4 / 256), 256, 0, stream>>>(k, v, kbuf, vtbuf);
  sparse_attn_v22<<<dim3(NBQ / 2 * HH), 512, 65536, stream>>>(q, kbuf, vtbuf, out);
}

// Round 24
// 96.070 us; speedup vs baseline: 1.1313x; 1.0615x over previous
//
#include <hip/hip_runtime.h>
#include <hip/hip_bf16.h>

#define HH 16
#define DD 128
#define NBQ 128
#define SS 8192

typedef __attribute__((ext_vector_type(4))) float f32x4;
typedef __attribute__((ext_vector_type(4))) short bf16x4;
typedef __attribute__((ext_vector_type(8))) short bf16x8;

// single-instruction HW convert (RNE)
__device__ __forceinline__ short f2bf_hw(float f) {
  __hip_bfloat16 b = __float2bfloat16(f);
  return __builtin_bit_cast(short, b);
}

__device__ __forceinline__ void gload_lds16(const void* g, void* l) {
  __builtin_amdgcn_global_load_lds(
      (const __attribute__((address_space(1))) void*)g,
      (__attribute__((address_space(3))) void*)l, 16, 0, 0);
}

// raw barrier with compile-time memory fences (no vmcnt drain)
__device__ __forceinline__ void wg_barrier() {
  asm volatile("" ::: "memory");
  __builtin_amdgcn_s_barrier();
  asm volatile("" ::: "memory");
}

// ---- GRID-fused prepass: blocks [0,2048) = V -> Vt3; [2048,4096) = K -> Kt2 ----
// FRAGMENT-ORDER layouts (zero main-kernel bank conflicts by construction):
//   Kt2 block (16KB): tile u = kt*4+kc (1KB each); slot s = lane = lg*16+l15 (16B each)
//     holds K[key = kt*16 + l15][d = kc*32 + lg*8 .. +7]  (QK A-fragment for lane s)
//   Vt3 block (16KB): tile u = nd*2+hb (1KB each); slot s = lane (16B each)
//     holds V[key = (2hb+(j>>2))*16 + lg*4 + (j&3)][d = nd*16+l15], j = 0..7
__global__ __launch_bounds__(256)
void conv_fused_kernel(const float* __restrict__ kg, const float* __restrict__ vg,
                       unsigned short* __restrict__ kt2, unsigned short* __restrict__ vt3) {
  __shared__ __align__(16) unsigned short tile[128 * 72];  // V: [d][key] padded; K: 16KB frag tile
  const int bx  = blockIdx.x;
  const int tid = threadIdx.x;
  if (bx < 2048) {
    // ---- V path: coalesced fp32 read -> padded [d][key] tile -> Vt3 coalesced write ----
    const int kb = bx & 127, h = bx >> 7;
    {
      const int r = tid >> 2, q = tid & 3;   // r = key row, q = d-chunk of 32
      const float* vp = vg + ((size_t)(kb * 64 + r) * HH + h) * DD + q * 32;
      #pragma unroll
      for (int c = 0; c < 8; ++c) {
        f32x4 a = *(const f32x4*)(vp + c * 4);
        #pragma unroll
        for (int j = 0; j < 4; ++j)
          tile[(q * 32 + c * 4 + j) * 72 + r] = (unsigned short)f2bf_hw(a[j]);
      }
    }
    __syncthreads();
    char* obase = (char*)vt3 + (((size_t)h * NBQ + kb) << 14);
    const int l15 = tid & 15, lg = (tid >> 4) & 3;
    #pragma unroll
    for (int round = 0; round < 4; ++round) {
      const int o  = round * 4096 + tid * 16;   // output byte offset (coalesced)
      const int u  = round * 4 + (tid >> 6);    // tile index
      const int nd = u >> 1, hb = u & 1;
      const int d  = nd * 16 + l15;
      bf16x8 f;
      #pragma unroll
      for (int j = 0; j < 8; ++j) {
        const int key = (2 * hb + (j >> 2)) * 16 + lg * 4 + (j & 3);
        f[j] = (short)tile[d * 72 + key];
      }
      *(bf16x8*)(obase + o) = f;
    }
  } else {
    // ---- K path: coalesced fp32 read -> cvt -> frag-order LDS tile -> coalesced write ----
    const int b2 = bx - 2048;
    const int kb = b2 & 127, h = b2 >> 7;
    {
      const int r = tid >> 2, q = tid & 3;   // r = key row, q = d-chunk of 32 (= kc)
      const float* kp = kg + ((size_t)(kb * 64 + r) * HH + h) * DD + q * 32;
      #pragma unroll
      for (int g = 0; g < 4; ++g) {          // g = lg (d-subchunk of 8)
        f32x4 a = *(const f32x4*)(kp + g * 8);
        f32x4 b = *(const f32x4*)(kp + g * 8 + 4);
        bf16x8 f;
        f[0] = f2bf_hw(a[0]); f[1] = f2bf_hw(a[1]); f[2] = f2bf_hw(a[2]); f[3] = f2bf_hw(a[3]);
        f[4] = f2bf_hw(b[0]); f[5] = f2bf_hw(b[1]); f[6] = f2bf_hw(b[2]); f[7] = f2bf_hw(b[3]);
        // tile u = (kt = r>>4)*4 + (kc = q); slot = (lg = g)*16 + (l15 = r&15)
        const int off = (((r >> 4) * 4 + q) * 64 + g * 16 + (r & 15)) * 8;  // in shorts
        *(bf16x8*)(&tile[off]) = f;
      }
    }
    __syncthreads();
    char* obase = (char*)kt2 + (((size_t)h * NBQ + kb) << 14);
    const char* tb = (const char*)tile;
    #pragma unroll
    for (int round = 0; round < 4; ++round) {
      const int o = round * 4096 + tid * 16;
      *(bf16x8*)(obase + o) = *(const bf16x8*)(tb + o);
    }
  }
}

// ---------- main kernel: v20/v22 skeleton + conflict-free fragment-order LDS ----------
// Single barrier per iter: vmcnt(0) [waits stage(t), issued a full iter ago -> ~free] ->
// barrier -> issue stage(t+1) -> compute(t). Linear gload (no swizzles). All QK/PV LDS
// reads are tile*1024 + lane*16 -> each wave reads 1KB contiguous: zero bank conflicts.
__global__ __launch_bounds__(512, 4)
void sparse_attn_v23(const float* __restrict__ qg_, const unsigned short* __restrict__ kt2,
                     const unsigned short* __restrict__ vt3, float* __restrict__ outg) {
  extern __shared__ __align__(16) char lds[];
  // K buf b: b*16384 (Kt2 frag order) | V buf b: 32768 + b*16384 (Vt3 frag order)

  const int bx   = blockIdx.x;
  const int w    = (bx & 7) * 128 + (bx >> 3);  // XCD-contiguous work index
  const int h    = w >> 6;
  const int qgrp = w & 63;
  const int tid  = threadIdx.x;
  const int wid  = tid >> 6;     // 0..7
  const int lane = tid & 63;
  const int l15  = lane & 15;
  const int lg   = lane >> 4;

  const int qlo  = qgrp * 2, qhi = qgrp * 2 + 1;
  const int qb_w = qlo + (wid >> 2);          // this wave's q-block (4 waves per block)
  const int rib0 = (wid & 3) * 16;            // wave's row base within its q-block

  const int nv     = (qhi + 1 < 4) ? qhi + 1 : 4;
  const int wstart = (qlo - 3 > 4) ? qlo - 3 : 4;
  const int nw     = (qhi - wstart + 1 > 0) ? qhi - wstart + 1 : 0;
  const int nlist  = nv + nw;                 // >= 2 always

  // 1/sqrt(128) * log2(e): exp2-domain softmax
  const float scale = 0.12752030522080552f;

  const int rowg = qgrp * 128 + (wid >> 2) * 64 + rib0;   // global row base of this wave
  const int lb   = lane * 16;                             // lane's byte slot within a tile

  // ---- Q fragments (B operand: col j = q-row = l15, k = d = kc*32+lg*8+{0..7}) ----
  bf16x8 qa[4];
  {
    const float* qp = qg_ + ((size_t)(rowg + l15) * HH + h) * DD;
    #pragma unroll
    for (int kc = 0; kc < 4; ++kc) {
      const int d0 = kc * 32 + lg * 8;
      f32x4 a = *(const f32x4*)(qp + d0);
      f32x4 b = *(const f32x4*)(qp + d0 + 4);
      bf16x8 f;
      f[0] = f2bf_hw(a[0] * scale); f[1] = f2bf_hw(a[1] * scale);
      f[2] = f2bf_hw(a[2] * scale); f[3] = f2bf_hw(a[3] * scale);
      f[4] = f2bf_hw(b[0] * scale); f[5] = f2bf_hw(b[1] * scale);
      f[6] = f2bf_hw(b[2] * scale); f[7] = f2bf_hw(b[3] * scale);
      qa[kc] = f;
    }
  }

  // oa[nd][r] = O[q-row = lg*4+r (within 16-row tile)][d = nd*16+l15]
  f32x4 oa[8];
  #pragma unroll
  for (int i = 0; i < 8; ++i) oa[i] = (f32x4){0.f, 0.f, 0.f, 0.f};
  float mr = -1e30f;   // running row max, keyed q-row = l15 (row-uniform)
  float lr = 0.f;      // lane-partial row sum, keyed l15

  const char* kbase = (const char*)kt2 + ((size_t)h * NBQ << 14);
  const char* vbase = (const char*)vt3 + ((size_t)h * NBQ << 14);
  const int o0 = wid * 1024 + lb;   // thread's 16B slot within an 8KB round (linear)

  // prologue: issue stage(0) into buf 0 (no wait; iter 0's vmcnt covers it)
  {
    #pragma unroll
    for (int p = 0; p < 2; ++p) {
      const int o = p * 8192 + o0;
      gload_lds16(kbase + o, lds + p * 8192 + wid * 1024);
    }
    #pragma unroll
    for (int p = 0; p < 2; ++p) {
      const int o = p * 8192 + o0;
      gload_lds16(vbase + o, lds + 32768 + p * 8192 + wid * 1024);
    }
  }

  for (int t = 0; t < nlist; ++t) {
    const int kb = (t < nv) ? t : (wstart + (t - nv));
    const bool valid = (kb <= qb_w) && ((qb_w - kb < 4) || (kb < 4));
    char* Kb = lds + (t & 1) * 16384;
    char* Vb = lds + 32768 + (t & 1) * 16384;
    const bool havenext = (t + 1 < nlist);

    // ---- wait own stage(t) (issued a full iteration ago -> ~free), then the single
    // ---- barrier: stage(t) visible everywhere AND compute(t-1) done ----
    asm volatile("s_waitcnt vmcnt(0)" ::: "memory");
    wg_barrier();

    // ---- issue stage(t+1) into the other buffers ----
    if (havenext) {
      const int kbn = (t + 1 < nv) ? (t + 1) : (wstart + (t + 1 - nv));
      const char* ksrc = kbase + ((size_t)kbn << 14);
      const char* vsrc = vbase + ((size_t)kbn << 14);
      char* Kd = lds + ((t + 1) & 1) * 16384;
      char* Vd = lds + 32768 + ((t + 1) & 1) * 16384;
      #pragma unroll
      for (int p = 0; p < 2; ++p) {
        const int o = p * 8192 + o0;
        gload_lds16(ksrc + o, Kd + p * 8192 + wid * 1024);
      }
      #pragma unroll
      for (int p = 0; p < 2; ++p) {
        const int o = p * 8192 + o0;
        gload_lds16(vsrc + o, Vd + p * 8192 + wid * 1024);
      }
    }

    if (valid) {
      // ---- S^T = K Q^T : s[kt][r] = S[q=l15][key = kt*16+lg*4+r] ----
      f32x4 s[4];
      #pragma unroll
      for (int kt = 0; kt < 4; ++kt) s[kt] = (f32x4){0.f, 0.f, 0.f, 0.f};
      __builtin_amdgcn_s_setprio(1);
      #pragma unroll
      for (int kt = 0; kt < 4; ++kt) {
        #pragma unroll
        for (int kc = 0; kc < 4; ++kc) {
          const int off = ((kt * 4 + kc) << 10) + lb;   // frag-order: contiguous per wave
          bf16x8 kf = *(const bf16x8*)(Kb + off);       // A: K[kt*16+l15][kc*32+lg*8..]
          s[kt] = __builtin_amdgcn_mfma_f32_16x16x32_bf16(kf, qa[kc], s[kt], 0, 0, 0);
        }
      }
      __builtin_amdgcn_s_setprio(0);

      // ---- diagonal block: element-level causal mask (q = l15, key = kt*16+lg*4+r) ----
      if (kb == qb_w) {
        const int rib = rib0 + l15;   // q-row within block
        #pragma unroll
        for (int kt = 0; kt < 4; ++kt)
          #pragma unroll
          for (int r = 0; r < 4; ++r) {
            const int key = kt * 16 + lg * 4 + r;
            if (rib < key) s[kt][r] = -1e30f;
          }
      }

      // ---- softmax (exp2 domain, defer-max THR=8, lane-partial sum) ----
      {
        float a0 = fmaxf(fmaxf(s[0][0], s[0][1]), fmaxf(s[0][2], s[0][3]));
        float a1 = fmaxf(fmaxf(s[1][0], s[1][1]), fmaxf(s[1][2], s[1][3]));
        float a2 = fmaxf(fmaxf(s[2][0], s[2][1]), fmaxf(s[2][2], s[2][3]));
        float a3 = fmaxf(fmaxf(s[3][0], s[3][1]), fmaxf(s[3][2], s[3][3]));
        float lanemax = fmaxf(fmaxf(a0, a1), fmaxf(a2, a3));
        if (!__all(lanemax <= mr + 8.f)) {
          float mx = lanemax;
          mx = fmaxf(mx, __shfl_xor(mx, 16));
          mx = fmaxf(mx, __shfl_xor(mx, 32));     // row max (uniform across lg)
          const float mnew = fmaxf(mr, mx);
          const float sc = __builtin_amdgcn_exp2f(mr - mnew);
          lr *= sc;
          mr = mnew;
          // transpose sc to oa rows: row (lg*4+r)'s sc lives in lane (lg*4+r)
          const float s0 = __shfl(sc, lg * 4 + 0);
          const float s1 = __shfl(sc, lg * 4 + 1);
          const float s2 = __shfl(sc, lg * 4 + 2);
          const float s3 = __shfl(sc, lg * 4 + 3);
          #pragma unroll
          for (int nd = 0; nd < 8; ++nd) {
            oa[nd][0] *= s0; oa[nd][1] *= s1;
            oa[nd][2] *= s2; oa[nd][3] *= s3;
          }
        }
        float lsum = 0.f;
        #pragma unroll
        for (int kt = 0; kt < 4; ++kt)
          #pragma unroll
          for (int r = 0; r < 4; ++r) {
            const float p = __builtin_amdgcn_exp2f(s[kt][r] - mr);
            s[kt][r] = p;
            lsum += p;
          }
        lr += lsum;
      }

      // ---- pack P in-register: pa[kt] = A-frag (row=l15, k=lg*4+{0..3}) ----
      bf16x4 pa[4];
      #pragma unroll
      for (int kt = 0; kt < 4; ++kt) {
        unsigned u0 = (unsigned)(unsigned short)f2bf_hw(s[kt][0]) |
                      ((unsigned)(unsigned short)f2bf_hw(s[kt][1]) << 16);
        unsigned u1 = (unsigned)(unsigned short)f2bf_hw(s[kt][2]) |
                      ((unsigned)(unsigned short)f2bf_hw(s[kt][3]) << 16);
        uint2 uu; uu.x = u0; uu.y = u1;
        pa[kt] = __builtin_bit_cast(bf16x4, uu);
      }

      // ---- O += P V : Vt3 frag-order b128 reads (contiguous per wave) ----
      __builtin_amdgcn_s_setprio(1);
      #pragma unroll
      for (int nd = 0; nd < 8; ++nd) {
        #pragma unroll
        for (int hb = 0; hb < 2; ++hb) {
          const int off = ((nd * 2 + hb) << 10) + lb;
          bf16x8 v2 = *(const bf16x8*)(Vb + off);
          bf16x4 vlo = __builtin_shufflevector(v2, v2, 0, 1, 2, 3);
          bf16x4 vhi = __builtin_shufflevector(v2, v2, 4, 5, 6, 7);
          oa[nd] = __builtin_amdgcn_mfma_f32_16x16x16bf16_1k(pa[2 * hb],     vlo, oa[nd], 0, 0, 0);
          oa[nd] = __builtin_amdgcn_mfma_f32_16x16x16bf16_1k(pa[2 * hb + 1], vhi, oa[nd], 0, 0, 0);
        }
      }
      __builtin_amdgcn_s_setprio(0);
    }
    // no trailing barrier: next iteration's single barrier provides the ordering
  }

  // ---- epilogue: reduce lr (keyed l15) across lg, transpose inv to oa rows, store ----
  {
    float l = lr;
    l += __shfl_xor(l, 16);
    l += __shfl_xor(l, 32);
    const float inv = 1.0f / l;                 // keyed l15
    const float i0 = __shfl(inv, lg * 4 + 0);   // row lg*4+r's inv from lane lg*4+r
    const float i1 = __shfl(inv, lg * 4 + 1);
    const float i2 = __shfl(inv, lg * 4 + 2);
    const float i3 = __shfl(inv, lg * 4 + 3);
    float* op = outg + ((size_t)rowg * HH + h) * DD;
    #pragma unroll
    for (int nd = 0; nd < 8; ++nd) {
      const int d = nd * 16 + l15;
      op[(size_t)(lg * 4 + 0) * HH * DD + d] = oa[nd][0] * i0;
      op[(size_t)(lg * 4 + 1) * HH * DD + d] = oa[nd][1] * i1;
      op[(size_t)(lg * 4 + 2) * HH * DD + d] = oa[nd][2] * i2;
      op[(size_t)(lg * 4 + 3) * HH * DD + d] = oa[nd][3] * i3;
    }
  }
}

extern "C" void kernel_launch(void* const* d_in, const int* in_sizes, int n_in,
                              void* d_out, int out_size, void* d_ws, size_t ws_size,
                              hipStream_t stream) {
  const float* q = (const float*)d_in[0];
  const float* k = (const float*)d_in[1];
  const float* v = (const float*)d_in[2];
  float* out = (float*)d_out;
  const size_t elems = (size_t)HH * SS * DD;
  unsigned short* kt2 = (unsigned short*)d_ws;
  unsigned short* vt3 = kt2 + elems;

  conv_fused_kernel<<<4096, 256, 0, stream>>>(k, v, kt2, vt3);
  sparse_attn_v23<<<dim3(NBQ / 2 * HH), 512, 65536, stream>>>(q, kt2, vt3, out);
}

// Round 25
// 95.601 us; speedup vs baseline: 1.1368x; 1.0049x over previous
//
#include <hip/hip_runtime.h>
#include <hip/hip_bf16.h>

#define HH 16
#define DD 128
#define NBQ 128
#define SS 8192

typedef __attribute__((ext_vector_type(4))) float f32x4;
typedef __attribute__((ext_vector_type(4))) short bf16x4;
typedef __attribute__((ext_vector_type(8))) short bf16x8;

// single-instruction HW convert (RNE)
__device__ __forceinline__ short f2bf_hw(float f) {
  __hip_bfloat16 b = __float2bfloat16(f);
  return __builtin_bit_cast(short, b);
}

__device__ __forceinline__ void gload_lds16(const void* g, void* l) {
  __builtin_amdgcn_global_load_lds(
      (const __attribute__((address_space(1))) void*)g,
      (__attribute__((address_space(3))) void*)l, 16, 0, 0);
}

// raw barrier with compile-time memory fences (no vmcnt drain)
__device__ __forceinline__ void wg_barrier() {
  asm volatile("" ::: "memory");
  __builtin_amdgcn_s_barrier();
  asm volatile("" ::: "memory");
}

// ---- GRID-fused prepass: blocks [0,2048) = V -> Vt3; [2048,4096) = K -> Kt2 ----
// FRAGMENT-ORDER layouts (zero main-kernel bank conflicts by construction):
//   Kt2 block (16KB): tile u = kt*4+kc (1KB); slot = lane (16B) holds
//     K[key = kt*16 + l15][d = kc*32 + lg*8 .. +7]
//   Vt3 block (16KB): tile u = nd*2+hb (1KB); slot = lane (16B) holds
//     V[key = (2hb+(j>>2))*16 + lg*4 + (j&3)][d = nd*16+l15], j = 0..7
__global__ __launch_bounds__(256)
void conv_fused_kernel(const float* __restrict__ kg, const float* __restrict__ vg,
                       unsigned short* __restrict__ kt2, unsigned short* __restrict__ vt3) {
  __shared__ __align__(16) unsigned short tile[128 * 72];  // V: [d][key] padded; K: 16KB frag tile
  const int bx  = blockIdx.x;
  const int tid = threadIdx.x;
  if (bx < 2048) {
    // ---- V path: coalesced fp32 read -> padded [d][key] tile -> Vt3 coalesced write ----
    const int kb = bx & 127, h = bx >> 7;
    {
      const int r = tid >> 2, q = tid & 3;   // r = key row, q = d-chunk of 32
      const float* vp = vg + ((size_t)(kb * 64 + r) * HH + h) * DD + q * 32;
      #pragma unroll
      for (int c = 0; c < 8; ++c) {
        f32x4 a = *(const f32x4*)(vp + c * 4);
        #pragma unroll
        for (int j = 0; j < 4; ++j)
          tile[(q * 32 + c * 4 + j) * 72 + r] = (unsigned short)f2bf_hw(a[j]);
      }
    }
    __syncthreads();
    char* obase = (char*)vt3 + (((size_t)h * NBQ + kb) << 14);
    const int l15 = tid & 15, lg = (tid >> 4) & 3;
    #pragma unroll
    for (int round = 0; round < 4; ++round) {
      const int o  = round * 4096 + tid * 16;   // output byte offset (coalesced)
      const int u  = round * 4 + (tid >> 6);    // tile index
      const int nd = u >> 1, hb = u & 1;
      const int d  = nd * 16 + l15;
      bf16x8 f;
      #pragma unroll
      for (int j = 0; j < 8; ++j) {
        const int key = (2 * hb + (j >> 2)) * 16 + lg * 4 + (j & 3);
        f[j] = (short)tile[d * 72 + key];
      }
      *(bf16x8*)(obase + o) = f;
    }
  } else {
    // ---- K path: coalesced fp32 read -> cvt -> frag-order LDS tile -> coalesced write ----
    const int b2 = bx - 2048;
    const int kb = b2 & 127, h = b2 >> 7;
    {
      const int r = tid >> 2, q = tid & 3;   // r = key row, q = d-chunk of 32 (= kc)
      const float* kp = kg + ((size_t)(kb * 64 + r) * HH + h) * DD + q * 32;
      #pragma unroll
      for (int g = 0; g < 4; ++g) {          // g = lg (d-subchunk of 8)
        f32x4 a = *(const f32x4*)(kp + g * 8);
        f32x4 b = *(const f32x4*)(kp + g * 8 + 4);
        bf16x8 f;
        f[0] = f2bf_hw(a[0]); f[1] = f2bf_hw(a[1]); f[2] = f2bf_hw(a[2]); f[3] = f2bf_hw(a[3]);
        f[4] = f2bf_hw(b[0]); f[5] = f2bf_hw(b[1]); f[6] = f2bf_hw(b[2]); f[7] = f2bf_hw(b[3]);
        const int off = (((r >> 4) * 4 + q) * 64 + g * 16 + (r & 15)) * 8;  // in shorts
        *(bf16x8*)(&tile[off]) = f;
      }
    }
    __syncthreads();
    char* obase = (char*)kt2 + (((size_t)h * NBQ + kb) << 14);
    const char* tb = (const char*)tile;
    #pragma unroll
    for (int round = 0; round < 4; ++round) {
      const int o = round * 4096 + tid * 16;
      *(bf16x8*)(obase + o) = *(const bf16x8*)(tb + o);
    }
  }
}

// ---------- main kernel: v23 core, NO setprio (A/B: m190 analog), max3-shaped reductions ----------
// Single barrier per iter: vmcnt(0) [waits stage(t), issued a full iter ago -> ~free] ->
// barrier -> issue stage(t+1) -> compute(t). Frag-order LDS: all reads tile*1024 + lane*16.
__global__ __launch_bounds__(512, 4)
void sparse_attn_v24(const float* __restrict__ qg_, const unsigned short* __restrict__ kt2,
                     const unsigned short* __restrict__ vt3, float* __restrict__ outg) {
  extern __shared__ __align__(16) char lds[];
  // K buf b: b*16384 (Kt2 frag order) | V buf b: 32768 + b*16384 (Vt3 frag order)

  const int bx   = blockIdx.x;
  const int w    = (bx & 7) * 128 + (bx >> 3);  // XCD-contiguous work index
  const int h    = w >> 6;
  const int qgrp = w & 63;
  const int tid  = threadIdx.x;
  const int wid  = tid >> 6;     // 0..7
  const int lane = tid & 63;
  const int l15  = lane & 15;
  const int lg   = lane >> 4;

  const int qlo  = qgrp * 2, qhi = qgrp * 2 + 1;
  const int qb_w = qlo + (wid >> 2);          // this wave's q-block (4 waves per block)
  const int rib0 = (wid & 3) * 16;            // wave's row base within its q-block

  const int nv     = (qhi + 1 < 4) ? qhi + 1 : 4;
  const int wstart = (qlo - 3 > 4) ? qlo - 3 : 4;
  const int nw     = (qhi - wstart + 1 > 0) ? qhi - wstart + 1 : 0;
  const int nlist  = nv + nw;                 // >= 2 always

  // 1/sqrt(128) * log2(e): exp2-domain softmax
  const float scale = 0.12752030522080552f;

  const int rowg = qgrp * 128 + (wid >> 2) * 64 + rib0;   // global row base of this wave
  const int lb   = lane * 16;                             // lane's byte slot within a tile

  // ---- Q fragments (B operand: col j = q-row = l15, k = d = kc*32+lg*8+{0..7}) ----
  bf16x8 qa[4];
  {
    const float* qp = qg_ + ((size_t)(rowg + l15) * HH + h) * DD;
    #pragma unroll
    for (int kc = 0; kc < 4; ++kc) {
      const int d0 = kc * 32 + lg * 8;
      f32x4 a = *(const f32x4*)(qp + d0);
      f32x4 b = *(const f32x4*)(qp + d0 + 4);
      bf16x8 f;
      f[0] = f2bf_hw(a[0] * scale); f[1] = f2bf_hw(a[1] * scale);
      f[2] = f2bf_hw(a[2] * scale); f[3] = f2bf_hw(a[3] * scale);
      f[4] = f2bf_hw(b[0] * scale); f[5] = f2bf_hw(b[1] * scale);
      f[6] = f2bf_hw(b[2] * scale); f[7] = f2bf_hw(b[3] * scale);
      qa[kc] = f;
    }
  }

  // oa[nd][r] = O[q-row = lg*4+r (within 16-row tile)][d = nd*16+l15]
  f32x4 oa[8];
  #pragma unroll
  for (int i = 0; i < 8; ++i) oa[i] = (f32x4){0.f, 0.f, 0.f, 0.f};
  float mr = -1e30f;   // running row max, keyed q-row = l15 (row-uniform)
  float lr = 0.f;      // lane-partial row sum, keyed l15

  const char* kbase = (const char*)kt2 + ((size_t)h * NBQ << 14);
  const char* vbase = (const char*)vt3 + ((size_t)h * NBQ << 14);
  const int o0 = wid * 1024 + lb;   // thread's 16B slot within an 8KB round (linear)

  // prologue: issue stage(0) into buf 0 (no wait; iter 0's vmcnt covers it)
  {
    #pragma unroll
    for (int p = 0; p < 2; ++p) {
      const int o = p * 8192 + o0;
      gload_lds16(kbase + o, lds + p * 8192 + wid * 1024);
    }
    #pragma unroll
    for (int p = 0; p < 2; ++p) {
      const int o = p * 8192 + o0;
      gload_lds16(vbase + o, lds + 32768 + p * 8192 + wid * 1024);
    }
  }

  for (int t = 0; t < nlist; ++t) {
    const int kb = (t < nv) ? t : (wstart + (t - nv));
    const bool valid = (kb <= qb_w) && ((qb_w - kb < 4) || (kb < 4));
    char* Kb = lds + (t & 1) * 16384;
    char* Vb = lds + 32768 + (t & 1) * 16384;
    const bool havenext = (t + 1 < nlist);

    // ---- wait own stage(t) (issued a full iteration ago -> ~free), then the single
    // ---- barrier: stage(t) visible everywhere AND compute(t-1) done ----
    asm volatile("s_waitcnt vmcnt(0)" ::: "memory");
    wg_barrier();

    // ---- issue stage(t+1) into the other buffers ----
    if (havenext) {
      const int kbn = (t + 1 < nv) ? (t + 1) : (wstart + (t + 1 - nv));
      const char* ksrc = kbase + ((size_t)kbn << 14);
      const char* vsrc = vbase + ((size_t)kbn << 14);
      char* Kd = lds + ((t + 1) & 1) * 16384;
      char* Vd = lds + 32768 + ((t + 1) & 1) * 16384;
      #pragma unroll
      for (int p = 0; p < 2; ++p) {
        const int o = p * 8192 + o0;
        gload_lds16(ksrc + o, Kd + p * 8192 + wid * 1024);
      }
      #pragma unroll
      for (int p = 0; p < 2; ++p) {
        const int o = p * 8192 + o0;
        gload_lds16(vsrc + o, Vd + p * 8192 + wid * 1024);
      }
    }

    if (valid) {
      // ---- S^T = K Q^T : s[kt][r] = S[q=l15][key = kt*16+lg*4+r] ----
      f32x4 s[4];
      #pragma unroll
      for (int kt = 0; kt < 4; ++kt) s[kt] = (f32x4){0.f, 0.f, 0.f, 0.f};
      #pragma unroll
      for (int kt = 0; kt < 4; ++kt) {
        #pragma unroll
        for (int kc = 0; kc < 4; ++kc) {
          const int off = ((kt * 4 + kc) << 10) + lb;   // frag-order: contiguous per wave
          bf16x8 kf = *(const bf16x8*)(Kb + off);       // A: K[kt*16+l15][kc*32+lg*8..]
          s[kt] = __builtin_amdgcn_mfma_f32_16x16x32_bf16(kf, qa[kc], s[kt], 0, 0, 0);
        }
      }

      // ---- diagonal block: element-level causal mask (q = l15, key = kt*16+lg*4+r) ----
      if (kb == qb_w) {
        const int rib = rib0 + l15;   // q-row within block
        #pragma unroll
        for (int kt = 0; kt < 4; ++kt)
          #pragma unroll
          for (int r = 0; r < 4; ++r) {
            const int key = kt * 16 + lg * 4 + r;
            if (rib < key) s[kt][r] = -1e30f;
          }
      }

      // ---- softmax (exp2 domain, defer-max THR=8, lane-partial sum) ----
      {
        // max3-shaped reduction: nested triples fuse to v_max3_f32
        float m01 = fmaxf(fmaxf(s[0][0], s[0][1]), fmaxf(fmaxf(s[0][2], s[0][3]), s[1][0]));
        float m02 = fmaxf(fmaxf(s[1][1], s[1][2]), fmaxf(fmaxf(s[1][3], s[2][0]), s[2][1]));
        float m03 = fmaxf(fmaxf(s[2][2], s[2][3]), fmaxf(fmaxf(s[3][0], s[3][1]), s[3][2]));
        float lanemax = fmaxf(fmaxf(m01, m02), fmaxf(m03, s[3][3]));
        if (!__all(lanemax <= mr + 8.f)) {
          float mx = lanemax;
          mx = fmaxf(mx, __shfl_xor(mx, 16));
          mx = fmaxf(mx, __shfl_xor(mx, 32));     // row max (uniform across lg)
          const float mnew = fmaxf(mr, mx);
          const float sc = __builtin_amdgcn_exp2f(mr - mnew);
          lr *= sc;
          mr = mnew;
          // transpose sc to oa rows: row (lg*4+r)'s sc lives in lane (lg*4+r)
          const float s0 = __shfl(sc, lg * 4 + 0);
          const float s1 = __shfl(sc, lg * 4 + 1);
          const float s2 = __shfl(sc, lg * 4 + 2);
          const float s3 = __shfl(sc, lg * 4 + 3);
          #pragma unroll
          for (int nd = 0; nd < 8; ++nd) {
            oa[nd][0] *= s0; oa[nd][1] *= s1;
            oa[nd][2] *= s2; oa[nd][3] *= s3;
          }
        }
        float lsum = 0.f;
        #pragma unroll
        for (int kt = 0; kt < 4; ++kt)
          #pragma unroll
          for (int r = 0; r < 4; ++r) {
            const float p = __builtin_amdgcn_exp2f(s[kt][r] - mr);
            s[kt][r] = p;
            lsum += p;
          }
        lr += lsum;
      }

      // ---- pack P in-register: pa[kt] = A-frag (row=l15, k=lg*4+{0..3}) ----
      bf16x4 pa[4];
      #pragma unroll
      for (int kt = 0; kt < 4; ++kt) {
        unsigned u0 = (unsigned)(unsigned short)f2bf_hw(s[kt][0]) |
                      ((unsigned)(unsigned short)f2bf_hw(s[kt][1]) << 16);
        unsigned u1 = (unsigned)(unsigned short)f2bf_hw(s[kt][2]) |
                      ((unsigned)(unsigned short)f2bf_hw(s[kt][3]) << 16);
        uint2 uu; uu.x = u0; uu.y = u1;
        pa[kt] = __builtin_bit_cast(bf16x4, uu);
      }

      // ---- O += P V : Vt3 frag-order b128 reads (contiguous per wave) ----
      #pragma unroll
      for (int nd = 0; nd < 8; ++nd) {
        #pragma unroll
        for (int hb = 0; hb < 2; ++hb) {
          const int off = ((nd * 2 + hb) << 10) + lb;
          bf16x8 v2 = *(const bf16x8*)(Vb + off);
          bf16x4 vlo = __builtin_shufflevector(v2, v2, 0, 1, 2, 3);
          bf16x4 vhi = __builtin_shufflevector(v2, v2, 4, 5, 6, 7);
          oa[nd] = __builtin_amdgcn_mfma_f32_16x16x16bf16_1k(pa[2 * hb],     vlo, oa[nd], 0, 0, 0);
          oa[nd] = __builtin_amdgcn_mfma_f32_16x16x16bf16_1k(pa[2 * hb + 1], vhi, oa[nd], 0, 0, 0);
        }
      }
    }
    // no trailing barrier: next iteration's single barrier provides the ordering
  }

  // ---- epilogue: reduce lr (keyed l15) across lg, transpose inv to oa rows, store ----
  {
    float l = lr;
    l += __shfl_xor(l, 16);
    l += __shfl_xor(l, 32);
    const float inv = 1.0f / l;                 // keyed l15
    const float i0 = __shfl(inv, lg * 4 + 0);   // row lg*4+r's inv from lane lg*4+r
    const float i1 = __shfl(inv, lg * 4 + 1);
    const float i2 = __shfl(inv, lg * 4 + 2);
    const float i3 = __shfl(inv, lg * 4 + 3);
    float* op = outg + ((size_t)rowg * HH + h) * DD;
    #pragma unroll
    for (int nd = 0; nd < 8; ++nd) {
      const int d = nd * 16 + l15;
      op[(size_t)(lg * 4 + 0) * HH * DD + d] = oa[nd][0] * i0;
      op[(size_t)(lg * 4 + 1) * HH * DD + d] = oa[nd][1] * i1;
      op[(size_t)(lg * 4 + 2) * HH * DD + d] = oa[nd][2] * i2;
      op[(size_t)(lg * 4 + 3) * HH * DD + d] = oa[nd][3] * i3;
    }
  }
}

extern "C" void kernel_launch(void* const* d_in, const int* in_sizes, int n_in,
                              void* d_out, int out_size, void* d_ws, size_t ws_size,
                              hipStream_t stream) {
  const float* q = (const float*)d_in[0];
  const float* k = (const float*)d_in[1];
  const float* v = (const float*)d_in[2];
  float* out = (float*)d_out;
  const size_t elems = (size_t)HH * SS * DD;
  unsigned short* kt2 = (unsigned short*)d_ws;
  unsigned short* vt3 = kt2 + elems;

  conv_fused_kernel<<<4096, 256, 0, stream>>>(k, v, kt2, vt3);
  sparse_attn_v24<<<dim3(NBQ / 2 * HH), 512, 65536, stream>>>(q, kt2, vt3, out);
}